// Round 1
// baseline (17392.516 us; speedup 1.0000x reference)
//
#include <hip/hip_runtime.h>

#define N_NODES  100000
#define N_EDGES  1600000
#define IN_DIM   500
#define HID      256
#define N_LAYERS 3
#define N_CLASSES 40

// ---------------------------------------------------------------------------
// Tiled fp32 GEMM: C[M,N] = A[M,K] @ B[K,N] (+bias)(+relu)
// MODE 0: C = A@B + bias
// MODE 1: C = relu(A@B + bias)
// MODE 2: C = A@B            and C2 = C * selfnorm[row]   (conv transform)
// Requirements used here: K % 4 == 0, N % 4 == 0 (true for all call sites:
// K in {500,256,128,64,32}, N in {256,128,64,32,40}).
// Block: 256 threads (16x16), 64x64 tile, 4x4 micro-tile, BK=16.
// ---------------------------------------------------------------------------
template <int MODE>
__global__ __launch_bounds__(256) void gemm_kernel(
    const float* __restrict__ A, const float* __restrict__ B,
    const float* __restrict__ bias, float* __restrict__ C,
    float* __restrict__ C2, const float* __restrict__ selfnorm,
    int M, int N, int K)
{
    __shared__ float As[16][68];   // As[k][m], stride 68 floats keeps 16B align + shifts banks
    __shared__ float Bs[16][68];   // Bs[k][n]

    const int tid = threadIdx.x;
    const int tx = tid & 15;       // micro-tile col group
    const int ty = tid >> 4;       // micro-tile row group
    const int bm = blockIdx.x * 64;
    const int bn = blockIdx.y * 64;

    // loader indices
    const int ar = tid >> 2;          // 0..63 : row within A tile
    const int ac = (tid & 3) * 4;     // 0,4,8,12 : k offset within A tile
    const int br = tid >> 4;          // 0..15 : k within B tile
    const int bc = (tid & 15) * 4;    // 0..60 : n offset within B tile

    float c[4][4] = {};

    for (int k0 = 0; k0 < K; k0 += 16) {
        // --- stage A tile (64 rows x 16 k) ---
        {
            const int m = bm + ar;
            const int k = k0 + ac;
            float4 av = make_float4(0.f, 0.f, 0.f, 0.f);
            if (m < M && k < K)                      // K%4==0 -> k+4 <= K
                av = *(const float4*)&A[m * K + k];
            As[ac + 0][ar] = av.x;
            As[ac + 1][ar] = av.y;
            As[ac + 2][ar] = av.z;
            As[ac + 3][ar] = av.w;
        }
        // --- stage B tile (16 k x 64 cols) ---
        {
            const int k = k0 + br;
            const int n = bn + bc;
            float4 bv = make_float4(0.f, 0.f, 0.f, 0.f);
            if (k < K && n < N)                      // N%4==0 -> n+4 <= N
                bv = *(const float4*)&B[k * N + n];
            Bs[br][bc + 0] = bv.x;
            Bs[br][bc + 1] = bv.y;
            Bs[br][bc + 2] = bv.z;
            Bs[br][bc + 3] = bv.w;
        }
        __syncthreads();

        #pragma unroll
        for (int kk = 0; kk < 16; ++kk) {
            const float4 av = *(const float4*)&As[kk][ty * 4];
            const float4 bv = *(const float4*)&Bs[kk][tx * 4];
            const float a[4] = {av.x, av.y, av.z, av.w};
            const float b[4] = {bv.x, bv.y, bv.z, bv.w};
            #pragma unroll
            for (int i = 0; i < 4; ++i)
                #pragma unroll
                for (int j = 0; j < 4; ++j)
                    c[i][j] = fmaf(a[i], b[j], c[i][j]);
        }
        __syncthreads();
    }

    // --- epilogue: vector stores (N%4==0) ---
    const int n = bn + tx * 4;
    if (n >= N) return;
    float4 bias4 = make_float4(0.f, 0.f, 0.f, 0.f);
    if (MODE == 0 || MODE == 1) bias4 = *(const float4*)&bias[n];

    #pragma unroll
    for (int i = 0; i < 4; ++i) {
        const int m = bm + ty * 4 + i;
        if (m >= M) continue;
        float4 v = make_float4(c[i][0], c[i][1], c[i][2], c[i][3]);
        if (MODE == 0 || MODE == 1) {
            v.x += bias4.x; v.y += bias4.y; v.z += bias4.z; v.w += bias4.w;
        }
        if (MODE == 1) {
            v.x = fmaxf(v.x, 0.f); v.y = fmaxf(v.y, 0.f);
            v.z = fmaxf(v.z, 0.f); v.w = fmaxf(v.w, 0.f);
        }
        *(float4*)&C[m * N + n] = v;
        if (MODE == 2) {
            const float sn = selfnorm[m];
            float4 w = make_float4(v.x * sn, v.y * sn, v.z * sn, v.w * sn);
            *(float4*)&C2[m * N + n] = w;
        }
    }
}

// ---------------------------------------------------------------------------
// degree: deg[dst[e]] += 1  (deg pre-zeroed)
// ---------------------------------------------------------------------------
__global__ __launch_bounds__(256) void deg_kernel(
    const int* __restrict__ dst, float* __restrict__ deg)
{
    const int i = blockIdx.x * 256 + threadIdx.x;
    if (i < N_EDGES) atomicAdd(&deg[dst[i]], 1.0f);
}

// dinv = 1/sqrt(deg+1), selfnorm = 1/(deg+1)
__global__ __launch_bounds__(256) void norm_kernel(
    const float* __restrict__ deg, float* __restrict__ dinv,
    float* __restrict__ selfnorm)
{
    const int i = blockIdx.x * 256 + threadIdx.x;
    if (i < N_NODES) {
        const float d = deg[i] + 1.0f;
        dinv[i] = 1.0f / sqrtf(d);
        selfnorm[i] = 1.0f / d;
    }
}

// ---------------------------------------------------------------------------
// Edge scatter: one 64-lane wave per edge; lane handles 4 contiguous floats.
// agg[dst] += hw[src] * (dinv[src]*dinv[dst])
// ---------------------------------------------------------------------------
__global__ __launch_bounds__(256) void scatter_kernel(
    const int* __restrict__ src, const int* __restrict__ dst,
    const float* __restrict__ dinv, const float* __restrict__ hw,
    float* __restrict__ agg)
{
    const int wave = (blockIdx.x * 256 + threadIdx.x) >> 6;
    const int lane = threadIdx.x & 63;
    if (wave >= N_EDGES) return;
    const int s = src[wave];
    const int d = dst[wave];
    const float w = dinv[s] * dinv[d];
    float4 v = *(const float4*)(hw + (size_t)s * HID + lane * 4);
    float* ap = agg + (size_t)d * HID + lane * 4;
    atomicAdd(ap + 0, v.x * w);
    atomicAdd(ap + 1, v.y * w);
    atomicAdd(ap + 2, v.z * w);
    atomicAdd(ap + 3, v.w * w);
}

// ---------------------------------------------------------------------------
// BN(eval) + relu + residual:  h = relu((agg + b)*gamma + beta) + h
// One float4 per thread over N_NODES*HID.
// ---------------------------------------------------------------------------
__global__ __launch_bounds__(256) void bn_res_kernel(
    float* __restrict__ h, const float* __restrict__ agg,
    const float* __restrict__ bias, const float* __restrict__ gamma,
    const float* __restrict__ beta)
{
    const long p = (long)blockIdx.x * 256 + threadIdx.x;  // float4 index
    const long total = (long)N_NODES * (HID / 4);
    if (p >= total) return;
    const int d = (int)(p & (HID / 4 - 1)) * 4;
    const float4 a  = ((const float4*)agg)[p];
    float4 hv       = ((float4*)h)[p];
    const float4 b4 = *(const float4*)&bias[d];
    const float4 g4 = *(const float4*)&gamma[d];
    const float4 t4 = *(const float4*)&beta[d];
    hv.x += fmaxf((a.x + b4.x) * g4.x + t4.x, 0.f);
    hv.y += fmaxf((a.y + b4.y) * g4.y + t4.y, 0.f);
    hv.z += fmaxf((a.z + b4.z) * g4.z + t4.z, 0.f);
    hv.w += fmaxf((a.w + b4.w) * g4.w + t4.w, 0.f);
    ((float4*)h)[p] = hv;
}

// ---------------------------------------------------------------------------
extern "C" void kernel_launch(void* const* d_in, const int* in_sizes, int n_in,
                              void* d_out, int out_size, void* d_ws, size_t ws_size,
                              hipStream_t stream)
{
    const float* x        = (const float*)d_in[0];
    const int*   ei       = (const int*)d_in[1];      // [2, E] row-major
    const float* embed_W  = (const float*)d_in[2];
    const float* embed_b  = (const float*)d_in[3];
    const float* conv_W   = (const float*)d_in[4];    // [3,256,256]
    const float* conv_b   = (const float*)d_in[5];    // [3,256]
    const float* bn_gamma = (const float*)d_in[6];
    const float* bn_beta  = (const float*)d_in[7];
    const float* cls_W0   = (const float*)d_in[8];
    const float* cls_b0   = (const float*)d_in[9];
    const float* cls_W1   = (const float*)d_in[10];
    const float* cls_b1   = (const float*)d_in[11];
    const float* cls_W2   = (const float*)d_in[12];
    const float* cls_b2   = (const float*)d_in[13];
    const float* cls_W3   = (const float*)d_in[14];
    const float* cls_b3   = (const float*)d_in[15];
    float* out = (float*)d_out;

    const int* e_src = ei;
    const int* e_dst = ei + N_EDGES;

    // workspace layout (floats)
    float* ws   = (float*)d_ws;
    float* deg  = ws;                       // [N]
    float* dinv = ws + N_NODES;             // [N]
    float* snorm= ws + 2 * N_NODES;         // [N]
    float* h    = ws + 3 * N_NODES;         // [N,256]
    float* hw   = h  + (size_t)N_NODES * HID;  // [N,256]
    float* agg  = hw + (size_t)N_NODES * HID;  // [N,256]

    // --- degree / norms (ws is poisoned each call -> zero deg) ---
    hipMemsetAsync(deg, 0, N_NODES * sizeof(float), stream);
    deg_kernel<<<(N_EDGES + 255) / 256, 256, 0, stream>>>(e_dst, deg);
    norm_kernel<<<(N_NODES + 255) / 256, 256, 0, stream>>>(deg, dinv, snorm);

    const int MT = (N_NODES + 63) / 64;   // 1563 row tiles

    // --- embed: h = x @ embed_W + embed_b ---
    gemm_kernel<0><<<dim3(MT, HID / 64), 256, 0, stream>>>(
        x, embed_W, embed_b, h, nullptr, nullptr, N_NODES, HID, IN_DIM);

    // --- GCN layers ---
    for (int l = 0; l < N_LAYERS; ++l) {
        // hw = h @ W_l ; agg = hw * selfnorm
        gemm_kernel<2><<<dim3(MT, HID / 64), 256, 0, stream>>>(
            h, conv_W + (size_t)l * HID * HID, nullptr, hw, agg, snorm,
            N_NODES, HID, HID);
        // agg[dst] += hw[src] * enorm
        scatter_kernel<<<(N_EDGES * 64 + 255) / 256, 256, 0, stream>>>(
            e_src, e_dst, dinv, hw, agg);
        // h = relu((agg + b)*gamma + beta) + h
        bn_res_kernel<<<(int)(((long)N_NODES * (HID / 4) + 255) / 256), 256, 0, stream>>>(
            h, agg, conv_b + l * HID, bn_gamma + l * HID, bn_beta + l * HID);
    }

    // --- classifier MLP (reuse hw/agg as ping-pong buffers) ---
    gemm_kernel<1><<<dim3(MT, 128 / 64), 256, 0, stream>>>(
        h, cls_W0, cls_b0, hw, nullptr, nullptr, N_NODES, 128, 256);
    gemm_kernel<1><<<dim3(MT, 1), 256, 0, stream>>>(
        hw, cls_W1, cls_b1, agg, nullptr, nullptr, N_NODES, 64, 128);
    gemm_kernel<1><<<dim3(MT, 1), 256, 0, stream>>>(
        agg, cls_W2, cls_b2, hw, nullptr, nullptr, N_NODES, 32, 64);
    gemm_kernel<0><<<dim3(MT, 1), 256, 0, stream>>>(
        hw, cls_W3, cls_b3, out, nullptr, nullptr, N_NODES, N_CLASSES, 32);
}

// Round 3
// 2281.787 us; speedup vs baseline: 7.6223x; 7.6223x over previous
//
#include <hip/hip_runtime.h>

#define N_NODES  100000
#define N_EDGES  1600000
#define IN_DIM   500
#define HID      256
#define N_LAYERS 3
#define N_CLASSES 40

// ---------------------------------------------------------------------------
// Tiled fp32 GEMM: C[M,N] = A[M,K] @ B[K,N]
// MODE 0: C = A@B + bias
// MODE 1: C = relu(A@B + bias)
// MODE 3: C = A@B               (conv transform, no bias)
// Block: 256 threads (16x16), 64x64 tile, 4x4 micro-tile, BK=16.
// ---------------------------------------------------------------------------
template <int MODE>
__global__ __launch_bounds__(256) void gemm_kernel(
    const float* __restrict__ A, const float* __restrict__ B,
    const float* __restrict__ bias, float* __restrict__ C,
    int M, int N, int K)
{
    __shared__ float As[16][68];   // As[k][m]
    __shared__ float Bs[16][68];   // Bs[k][n]

    const int tid = threadIdx.x;
    const int tx = tid & 15;
    const int ty = tid >> 4;
    const int bm = blockIdx.x * 64;
    const int bn = blockIdx.y * 64;

    const int ar = tid >> 2;          // 0..63 : row within A tile
    const int ac = (tid & 3) * 4;     // 0,4,8,12 : k offset within A tile
    const int br = tid >> 4;          // 0..15 : k within B tile
    const int bc = (tid & 15) * 4;    // 0..60 : n offset within B tile

    float c[4][4] = {};

    for (int k0 = 0; k0 < K; k0 += 16) {
        {
            const int m = bm + ar;
            const int k = k0 + ac;
            float4 av = make_float4(0.f, 0.f, 0.f, 0.f);
            if (m < M && k < K) av = *(const float4*)&A[(size_t)m * K + k];
            As[ac + 0][ar] = av.x;
            As[ac + 1][ar] = av.y;
            As[ac + 2][ar] = av.z;
            As[ac + 3][ar] = av.w;
        }
        {
            const int k = k0 + br;
            const int n = bn + bc;
            float4 bv = make_float4(0.f, 0.f, 0.f, 0.f);
            if (k < K && n < N) bv = *(const float4*)&B[(size_t)k * N + n];
            Bs[br][bc + 0] = bv.x;
            Bs[br][bc + 1] = bv.y;
            Bs[br][bc + 2] = bv.z;
            Bs[br][bc + 3] = bv.w;
        }
        __syncthreads();

        #pragma unroll
        for (int kk = 0; kk < 16; ++kk) {
            const float4 av = *(const float4*)&As[kk][ty * 4];
            const float4 bv = *(const float4*)&Bs[kk][tx * 4];
            const float a[4] = {av.x, av.y, av.z, av.w};
            const float b[4] = {bv.x, bv.y, bv.z, bv.w};
            #pragma unroll
            for (int i = 0; i < 4; ++i)
                #pragma unroll
                for (int j = 0; j < 4; ++j)
                    c[i][j] = fmaf(a[i], b[j], c[i][j]);
        }
        __syncthreads();
    }

    const int n = bn + tx * 4;
    if (n >= N) return;
    float4 bias4 = make_float4(0.f, 0.f, 0.f, 0.f);
    if (MODE == 0 || MODE == 1) bias4 = *(const float4*)&bias[n];

    #pragma unroll
    for (int i = 0; i < 4; ++i) {
        const int m = bm + ty * 4 + i;
        if (m >= M) continue;
        float4 v = make_float4(c[i][0], c[i][1], c[i][2], c[i][3]);
        if (MODE == 0 || MODE == 1) {
            v.x += bias4.x; v.y += bias4.y; v.z += bias4.z; v.w += bias4.w;
        }
        if (MODE == 1) {
            v.x = fmaxf(v.x, 0.f); v.y = fmaxf(v.y, 0.f);
            v.z = fmaxf(v.z, 0.f); v.w = fmaxf(v.w, 0.f);
        }
        *(float4*)&C[(size_t)m * N + n] = v;
    }
}

// ---------------------------------------------------------------------------
// degree histogram over dst (int, deg pre-zeroed)
// ---------------------------------------------------------------------------
__global__ __launch_bounds__(256) void deg_kernel(
    const int* __restrict__ dst, int* __restrict__ deg)
{
    const int i = blockIdx.x * 256 + threadIdx.x;
    if (i < N_EDGES) atomicAdd(&deg[dst[i]], 1);
}

// dinv = 1/sqrt(deg+1), selfnorm = 1/(deg+1)
__global__ __launch_bounds__(256) void norm_kernel(
    const int* __restrict__ deg, float* __restrict__ dinv,
    float* __restrict__ selfnorm)
{
    const int i = blockIdx.x * 256 + threadIdx.x;
    if (i < N_NODES) {
        const float d = (float)deg[i] + 1.0f;
        dinv[i] = 1.0f / sqrtf(d);
        selfnorm[i] = 1.0f / d;
    }
}

// ---------------------------------------------------------------------------
// 3-step exclusive scan of deg -> offs
// ---------------------------------------------------------------------------
__global__ __launch_bounds__(256) void scan1_kernel(
    const int* __restrict__ deg, int* __restrict__ offs,
    int* __restrict__ bsum, int n)
{
    __shared__ int tmp[256];
    const int i = blockIdx.x * 256 + threadIdx.x;
    const int v = (i < n) ? deg[i] : 0;
    tmp[threadIdx.x] = v;
    __syncthreads();
    #pragma unroll
    for (int off = 1; off < 256; off <<= 1) {
        const int t = (threadIdx.x >= off) ? tmp[threadIdx.x - off] : 0;
        __syncthreads();
        tmp[threadIdx.x] += t;
        __syncthreads();
    }
    const int inc = tmp[threadIdx.x];
    if (i < n) offs[i] = inc - v;               // exclusive
    if (threadIdx.x == 255) bsum[blockIdx.x] = inc;
}

__global__ __launch_bounds__(512) void scan2_kernel(int* __restrict__ bsum, int nb)
{
    __shared__ int tmp[512];
    const int i = threadIdx.x;
    const int v = (i < nb) ? bsum[i] : 0;
    tmp[i] = v;
    __syncthreads();
    #pragma unroll
    for (int off = 1; off < 512; off <<= 1) {
        const int t = (i >= off) ? tmp[i - off] : 0;
        __syncthreads();
        tmp[i] += t;
        __syncthreads();
    }
    if (i < nb) bsum[i] = tmp[i] - v;           // exclusive block prefix
}

__global__ __launch_bounds__(256) void scan3_kernel(
    int* __restrict__ offs, const int* __restrict__ bsum, int n)
{
    const int i = blockIdx.x * 256 + threadIdx.x;
    if (i < n) offs[i] += bsum[blockIdx.x];
}

// ---------------------------------------------------------------------------
// CSR bucket fill: csr_src[pos]=src, csr_w[pos]=dinv[src]*dinv[dst]
// ---------------------------------------------------------------------------
__global__ __launch_bounds__(256) void fill_kernel(
    const int* __restrict__ src, const int* __restrict__ dst,
    const int* __restrict__ offs, int* __restrict__ fill,
    const float* __restrict__ dinv,
    int* __restrict__ csr_src, float* __restrict__ csr_w)
{
    const int e = blockIdx.x * 256 + threadIdx.x;
    if (e >= N_EDGES) return;
    const int s = src[e];
    const int d = dst[e];
    const int pos = offs[d] + atomicAdd(&fill[d], 1);
    csr_src[pos] = s;
    csr_w[pos] = dinv[s] * dinv[d];
}

// ---------------------------------------------------------------------------
// Fused gather + self-loop + bias + BN(eval) + relu + residual.
// One 64-lane wave per destination node; lane owns 4 contiguous floats.
//   acc = sum_e hw[src_e]*w_e + hw[d]*snorm[d]
//   h[d] = relu((acc + b)*gamma + beta) + h[d]
// ---------------------------------------------------------------------------
__global__ __launch_bounds__(256) void gather_fused_kernel(
    const int* __restrict__ offs, const int* __restrict__ degi,
    const int* __restrict__ csr_src, const float* __restrict__ csr_w,
    const float* __restrict__ hw, const float* __restrict__ snorm,
    const float* __restrict__ bias, const float* __restrict__ gamma,
    const float* __restrict__ beta, float* __restrict__ h)
{
    const int w = (blockIdx.x * 256 + threadIdx.x) >> 6;
    const int lane = threadIdx.x & 63;
    if (w >= N_NODES) return;
    const int start = offs[w];
    const int cnt = degi[w];
    const int col = lane * 4;

    float4 acc = make_float4(0.f, 0.f, 0.f, 0.f);
    int i = 0;
    for (; i + 2 <= cnt; i += 2) {
        const int   s0 = csr_src[start + i];
        const int   s1 = csr_src[start + i + 1];
        const float w0 = csr_w[start + i];
        const float w1 = csr_w[start + i + 1];
        const float4 v0 = *(const float4*)(hw + (size_t)s0 * HID + col);
        const float4 v1 = *(const float4*)(hw + (size_t)s1 * HID + col);
        acc.x = fmaf(v0.x, w0, acc.x); acc.y = fmaf(v0.y, w0, acc.y);
        acc.z = fmaf(v0.z, w0, acc.z); acc.w = fmaf(v0.w, w0, acc.w);
        acc.x = fmaf(v1.x, w1, acc.x); acc.y = fmaf(v1.y, w1, acc.y);
        acc.z = fmaf(v1.z, w1, acc.z); acc.w = fmaf(v1.w, w1, acc.w);
    }
    if (i < cnt) {
        const int   s0 = csr_src[start + i];
        const float w0 = csr_w[start + i];
        const float4 v0 = *(const float4*)(hw + (size_t)s0 * HID + col);
        acc.x = fmaf(v0.x, w0, acc.x); acc.y = fmaf(v0.y, w0, acc.y);
        acc.z = fmaf(v0.z, w0, acc.z); acc.w = fmaf(v0.w, w0, acc.w);
    }

    // self-loop term
    const float sn = snorm[w];
    const float4 hwv = *(const float4*)(hw + (size_t)w * HID + col);
    acc.x = fmaf(hwv.x, sn, acc.x); acc.y = fmaf(hwv.y, sn, acc.y);
    acc.z = fmaf(hwv.z, sn, acc.z); acc.w = fmaf(hwv.w, sn, acc.w);

    // bias + BN + relu + residual
    const float4 b4 = *(const float4*)&bias[col];
    const float4 g4 = *(const float4*)&gamma[col];
    const float4 t4 = *(const float4*)&beta[col];
    float* hp = h + (size_t)w * HID + col;
    float4 hv = *(float4*)hp;
    hv.x += fmaxf((acc.x + b4.x) * g4.x + t4.x, 0.f);
    hv.y += fmaxf((acc.y + b4.y) * g4.y + t4.y, 0.f);
    hv.z += fmaxf((acc.z + b4.z) * g4.z + t4.z, 0.f);
    hv.w += fmaxf((acc.w + b4.w) * g4.w + t4.w, 0.f);
    *(float4*)hp = hv;
}

// ---------------------------------------------------------------------------
extern "C" void kernel_launch(void* const* d_in, const int* in_sizes, int n_in,
                              void* d_out, int out_size, void* d_ws, size_t ws_size,
                              hipStream_t stream)
{
    const float* x        = (const float*)d_in[0];
    const int*   ei       = (const int*)d_in[1];      // [2, E]
    const float* embed_W  = (const float*)d_in[2];
    const float* embed_b  = (const float*)d_in[3];
    const float* conv_W   = (const float*)d_in[4];    // [3,256,256]
    const float* conv_b   = (const float*)d_in[5];
    const float* bn_gamma = (const float*)d_in[6];
    const float* bn_beta  = (const float*)d_in[7];
    const float* cls_W0   = (const float*)d_in[8];
    const float* cls_b0   = (const float*)d_in[9];
    const float* cls_W1   = (const float*)d_in[10];
    const float* cls_b1   = (const float*)d_in[11];
    const float* cls_W2   = (const float*)d_in[12];
    const float* cls_b2   = (const float*)d_in[13];
    const float* cls_W3   = (const float*)d_in[14];
    const float* cls_b3   = (const float*)d_in[15];
    float* out = (float*)d_out;

    const int* e_src = ei;
    const int* e_dst = ei + N_EDGES;

    // ---- workspace layout ----
    char* p = (char*)d_ws;
    int*   deg_i   = (int*)p;                 p += (size_t)N_NODES * 4;   // must be
    int*   fillc   = (int*)p;                 p += (size_t)N_NODES * 4;   // adjacent (1 memset)
    int*   offs    = (int*)p;                 p += (size_t)N_NODES * 4;
    int*   bsum    = (int*)p;                 p += 512 * 4;
    float* dinv    = (float*)p;               p += (size_t)N_NODES * 4;
    float* snorm   = (float*)p;               p += (size_t)N_NODES * 4;
    int*   csr_src = (int*)p;                 p += (size_t)N_EDGES * 4;
    float* csr_w   = (float*)p;               p += (size_t)N_EDGES * 4;
    float* h       = (float*)p;               p += (size_t)N_NODES * HID * 4;
    float* hw      = (float*)p;               p += (size_t)N_NODES * HID * 4;
    float* mlpA    = (float*)p;               p += (size_t)N_NODES * 128 * 4;
    float* mlpB    = (float*)p;               p += (size_t)N_NODES * 64 * 4;

    const int NB_N = (N_NODES + 255) / 256;   // 391
    const int NB_E = (N_EDGES + 255) / 256;   // 6250

    // ---- degree / norms / CSR build (ws re-poisoned each call) ----
    hipMemsetAsync(deg_i, 0, (size_t)2 * N_NODES * sizeof(int), stream);
    deg_kernel<<<NB_E, 256, 0, stream>>>(e_dst, deg_i);
    norm_kernel<<<NB_N, 256, 0, stream>>>(deg_i, dinv, snorm);
    scan1_kernel<<<NB_N, 256, 0, stream>>>(deg_i, offs, bsum, N_NODES);
    scan2_kernel<<<1, 512, 0, stream>>>(bsum, NB_N);
    scan3_kernel<<<NB_N, 256, 0, stream>>>(offs, bsum, N_NODES);
    fill_kernel<<<NB_E, 256, 0, stream>>>(e_src, e_dst, offs, fillc, dinv,
                                          csr_src, csr_w);

    const int MT = (N_NODES + 63) / 64;   // 1563 row tiles

    // ---- embed: h = x @ embed_W + embed_b ----
    gemm_kernel<0><<<dim3(MT, HID / 64), 256, 0, stream>>>(
        x, embed_W, embed_b, h, N_NODES, HID, IN_DIM);

    // ---- GCN layers ----
    for (int l = 0; l < N_LAYERS; ++l) {
        gemm_kernel<3><<<dim3(MT, HID / 64), 256, 0, stream>>>(
            h, conv_W + (size_t)l * HID * HID, nullptr, hw, N_NODES, HID, HID);
        gather_fused_kernel<<<(N_NODES * 64 + 255) / 256, 256, 0, stream>>>(
            offs, deg_i, csr_src, csr_w, hw, snorm,
            conv_b + l * HID, bn_gamma + l * HID, bn_beta + l * HID, h);
    }

    // ---- classifier MLP ----
    gemm_kernel<1><<<dim3(MT, 2), 256, 0, stream>>>(
        h, cls_W0, cls_b0, mlpA, N_NODES, 128, 256);
    gemm_kernel<1><<<dim3(MT, 1), 256, 0, stream>>>(
        mlpA, cls_W1, cls_b1, mlpB, N_NODES, 64, 128);
    gemm_kernel<1><<<dim3(MT, 1), 256, 0, stream>>>(
        mlpB, cls_W2, cls_b2, mlpA, N_NODES, 32, 64);
    gemm_kernel<0><<<dim3(MT, 1), 256, 0, stream>>>(
        mlpA, cls_W3, cls_b3, out, N_NODES, N_CLASSES, 32);
}

// Round 4
// 1305.724 us; speedup vs baseline: 13.3202x; 1.7475x over previous
//
#include <hip/hip_runtime.h>

#define N_NODES  100000
#define N_EDGES  1600000
#define IN_DIM   500
#define HID      256
#define N_LAYERS 3
#define N_CLASSES 40

typedef _Float16 f16;
typedef __attribute__((ext_vector_type(8))) _Float16 f16x8;
typedef __attribute__((ext_vector_type(4))) _Float16 f16x4;
typedef __attribute__((ext_vector_type(4))) float    f32x4;

// ---------------------------------------------------------------------------
// MFMA fp16 GEMM: C[M,N] = A[M,K](fp32, converted in-staging) @ Bt[N,KP](fp16)
// MODE 0: fp32 out + bias     MODE 1: fp32 out + bias + relu
// MODE 4: fp16 out, no bias   (conv transform -> hw)
// Block 256 thr = 4 waves (2x2), tile 128x128, BK=32.
// Requires: N0 = gridDim.y*128 == N exactly (all call sites: N in {256,128}).
// ---------------------------------------------------------------------------
template <int MODE>
__global__ __launch_bounds__(256) void mfma_gemm_kernel(
    const float* __restrict__ A, const f16* __restrict__ Bt,
    const float* __restrict__ bias, void* __restrict__ Cout,
    int M, int N, int K, int KP)
{
    __shared__ f16 Ah[128][32];
    __shared__ f16 Bs[128][32];

    const int tid  = threadIdx.x;
    const int lane = tid & 63;
    const int w    = tid >> 6;
    const int wr   = w >> 1;          // wave row (0..1) -> 64 rows
    const int wc   = w & 1;           // wave col (0..1) -> 64 cols
    const int m0   = blockIdx.x * 128;
    const int n0   = blockIdx.y * 128;

    const int srow = tid >> 2;        // 0..63 staging row
    const int sc8  = tid & 3;         // which 8-half chunk (0..3)

    f32x4 acc[4][4];
    #pragma unroll
    for (int i = 0; i < 4; ++i)
        #pragma unroll
        for (int j = 0; j < 4; ++j)
            acc[i][j] = (f32x4){0.f, 0.f, 0.f, 0.f};

    for (int k0 = 0; k0 < KP; k0 += 32) {
        // ---- stage A (fp32 -> fp16), rows srow, srow+64 ----
        #pragma unroll
        for (int i = 0; i < 2; ++i) {
            const int r = srow + 64 * i;
            const int m = m0 + r;
            const int k = k0 + sc8 * 8;
            float4 lo = make_float4(0.f, 0.f, 0.f, 0.f);
            float4 hi = make_float4(0.f, 0.f, 0.f, 0.f);
            if (m < M) {
                if (k + 4 <= K) lo = *(const float4*)&A[(size_t)m * K + k];
                if (k + 8 <= K) hi = *(const float4*)&A[(size_t)m * K + k + 4];
            }
            f16x8 hv;
            hv[0] = (f16)lo.x; hv[1] = (f16)lo.y; hv[2] = (f16)lo.z; hv[3] = (f16)lo.w;
            hv[4] = (f16)hi.x; hv[5] = (f16)hi.y; hv[6] = (f16)hi.z; hv[7] = (f16)hi.w;
            *(f16x8*)&Ah[r][sc8 * 8] = hv;
        }
        // ---- stage Bt (already fp16, zero-padded to KP) ----
        #pragma unroll
        for (int i = 0; i < 2; ++i) {
            const int r = srow + 64 * i;
            *(f16x8*)&Bs[r][sc8 * 8] =
                *(const f16x8*)&Bt[(size_t)(n0 + r) * KP + k0 + sc8 * 8];
        }
        __syncthreads();

        // ---- fragments + MFMA ----
        const int fr = lane & 15;
        const int fg = (lane >> 4) * 8;
        f16x8 af[4], bf[4];
        #pragma unroll
        for (int i = 0; i < 4; ++i)
            af[i] = *(const f16x8*)&Ah[wr * 64 + i * 16 + fr][fg];
        #pragma unroll
        for (int j = 0; j < 4; ++j)
            bf[j] = *(const f16x8*)&Bs[wc * 64 + j * 16 + fr][fg];
        #pragma unroll
        for (int i = 0; i < 4; ++i)
            #pragma unroll
            for (int j = 0; j < 4; ++j)
                acc[i][j] = __builtin_amdgcn_mfma_f32_16x16x32_f16(
                    af[i], bf[j], acc[i][j], 0, 0, 0);
        __syncthreads();
    }

    // ---- epilogue: C/D layout col=lane&15, row=(lane>>4)*4+reg ----
    const int fr = lane & 15;
    const int rg = (lane >> 4) * 4;
    #pragma unroll
    for (int i = 0; i < 4; ++i) {
        const int mrow = m0 + wr * 64 + i * 16 + rg;
        #pragma unroll
        for (int j = 0; j < 4; ++j) {
            const int col = n0 + wc * 64 + j * 16 + fr;
            const float b = (MODE == 0 || MODE == 1) ? bias[col] : 0.f;
            #pragma unroll
            for (int r = 0; r < 4; ++r) {
                const int m = mrow + r;
                if (m >= M) continue;
                float v = acc[i][j][r] + b;
                if (MODE == 1) v = fmaxf(v, 0.f);
                if (MODE == 4) ((f16*)Cout)[(size_t)m * N + col] = (f16)v;
                else           ((float*)Cout)[(size_t)m * N + col] = v;
            }
        }
    }
}

// ---------------------------------------------------------------------------
// Weight transpose + fp16 convert: W[K][N] fp32 -> Wt[N][KP] fp16 (zero pad)
// ---------------------------------------------------------------------------
__global__ __launch_bounds__(256) void wt_kernel(
    const float* __restrict__ W, f16* __restrict__ Wt, int K, int N, int KP)
{
    const int i = blockIdx.x * 256 + threadIdx.x;
    if (i >= N * KP) return;
    const int n = i / KP;
    const int k = i - n * KP;
    Wt[i] = (k < K) ? (f16)W[(size_t)k * N + n] : (f16)0.f;
}

// ---------------------------------------------------------------------------
// Tiled fp32 GEMM for the small MLP tail (N<=64).
// MODE 0: C = A@B + bias   MODE 1: C = relu(A@B + bias)
// ---------------------------------------------------------------------------
template <int MODE>
__global__ __launch_bounds__(256) void gemm_kernel(
    const float* __restrict__ A, const float* __restrict__ B,
    const float* __restrict__ bias, float* __restrict__ C,
    int M, int N, int K)
{
    __shared__ float As[16][68];
    __shared__ float Bsh[16][68];

    const int tid = threadIdx.x;
    const int tx = tid & 15;
    const int ty = tid >> 4;
    const int bm = blockIdx.x * 64;
    const int bn = blockIdx.y * 64;

    const int ar = tid >> 2;
    const int ac = (tid & 3) * 4;
    const int br = tid >> 4;
    const int bc = (tid & 15) * 4;

    float c[4][4] = {};

    for (int k0 = 0; k0 < K; k0 += 16) {
        {
            const int m = bm + ar;
            const int k = k0 + ac;
            float4 av = make_float4(0.f, 0.f, 0.f, 0.f);
            if (m < M && k < K) av = *(const float4*)&A[(size_t)m * K + k];
            As[ac + 0][ar] = av.x;
            As[ac + 1][ar] = av.y;
            As[ac + 2][ar] = av.z;
            As[ac + 3][ar] = av.w;
        }
        {
            const int k = k0 + br;
            const int n = bn + bc;
            float4 bv = make_float4(0.f, 0.f, 0.f, 0.f);
            if (k < K && n < N) bv = *(const float4*)&B[(size_t)k * N + n];
            Bsh[br][bc + 0] = bv.x;
            Bsh[br][bc + 1] = bv.y;
            Bsh[br][bc + 2] = bv.z;
            Bsh[br][bc + 3] = bv.w;
        }
        __syncthreads();

        #pragma unroll
        for (int kk = 0; kk < 16; ++kk) {
            const float4 av = *(const float4*)&As[kk][ty * 4];
            const float4 bv = *(const float4*)&Bsh[kk][tx * 4];
            const float a[4] = {av.x, av.y, av.z, av.w};
            const float b[4] = {bv.x, bv.y, bv.z, bv.w};
            #pragma unroll
            for (int i = 0; i < 4; ++i)
                #pragma unroll
                for (int j = 0; j < 4; ++j)
                    c[i][j] = fmaf(a[i], b[j], c[i][j]);
        }
        __syncthreads();
    }

    const int n = bn + tx * 4;
    if (n >= N) return;
    const float4 bias4 = *(const float4*)&bias[n];

    #pragma unroll
    for (int i = 0; i < 4; ++i) {
        const int m = bm + ty * 4 + i;
        if (m >= M) continue;
        float4 v = make_float4(c[i][0] + bias4.x, c[i][1] + bias4.y,
                               c[i][2] + bias4.z, c[i][3] + bias4.w);
        if (MODE == 1) {
            v.x = fmaxf(v.x, 0.f); v.y = fmaxf(v.y, 0.f);
            v.z = fmaxf(v.z, 0.f); v.w = fmaxf(v.w, 0.f);
        }
        *(float4*)&C[(size_t)m * N + n] = v;
    }
}

// ---------------------------------------------------------------------------
// degree histogram over dst (int, deg pre-zeroed)
// ---------------------------------------------------------------------------
__global__ __launch_bounds__(256) void deg_kernel(
    const int* __restrict__ dst, int* __restrict__ deg)
{
    const int i = blockIdx.x * 256 + threadIdx.x;
    if (i < N_EDGES) atomicAdd(&deg[dst[i]], 1);
}

__global__ __launch_bounds__(256) void norm_kernel(
    const int* __restrict__ deg, float* __restrict__ dinv,
    float* __restrict__ selfnorm)
{
    const int i = blockIdx.x * 256 + threadIdx.x;
    if (i < N_NODES) {
        const float d = (float)deg[i] + 1.0f;
        dinv[i] = 1.0f / sqrtf(d);
        selfnorm[i] = 1.0f / d;
    }
}

// ---------------------------------------------------------------------------
// 3-step exclusive scan of deg -> offs
// ---------------------------------------------------------------------------
__global__ __launch_bounds__(256) void scan1_kernel(
    const int* __restrict__ deg, int* __restrict__ offs,
    int* __restrict__ bsum, int n)
{
    __shared__ int tmp[256];
    const int i = blockIdx.x * 256 + threadIdx.x;
    const int v = (i < n) ? deg[i] : 0;
    tmp[threadIdx.x] = v;
    __syncthreads();
    #pragma unroll
    for (int off = 1; off < 256; off <<= 1) {
        const int t = (threadIdx.x >= off) ? tmp[threadIdx.x - off] : 0;
        __syncthreads();
        tmp[threadIdx.x] += t;
        __syncthreads();
    }
    const int inc = tmp[threadIdx.x];
    if (i < n) offs[i] = inc - v;
    if (threadIdx.x == 255) bsum[blockIdx.x] = inc;
}

__global__ __launch_bounds__(512) void scan2_kernel(int* __restrict__ bsum, int nb)
{
    __shared__ int tmp[512];
    const int i = threadIdx.x;
    const int v = (i < nb) ? bsum[i] : 0;
    tmp[i] = v;
    __syncthreads();
    #pragma unroll
    for (int off = 1; off < 512; off <<= 1) {
        const int t = (i >= off) ? tmp[i - off] : 0;
        __syncthreads();
        tmp[i] += t;
        __syncthreads();
    }
    if (i < nb) bsum[i] = tmp[i] - v;
}

__global__ __launch_bounds__(256) void scan3_kernel(
    int* __restrict__ offs, const int* __restrict__ bsum, int n)
{
    const int i = blockIdx.x * 256 + threadIdx.x;
    if (i < n) offs[i] += bsum[blockIdx.x];
}

// ---------------------------------------------------------------------------
// CSR bucket fill
// ---------------------------------------------------------------------------
__global__ __launch_bounds__(256) void fill_kernel(
    const int* __restrict__ src, const int* __restrict__ dst,
    const int* __restrict__ offs, int* __restrict__ fill,
    const float* __restrict__ dinv,
    int* __restrict__ csr_src, float* __restrict__ csr_w)
{
    const int e = blockIdx.x * 256 + threadIdx.x;
    if (e >= N_EDGES) return;
    const int s = src[e];
    const int d = dst[e];
    const int pos = offs[d] + atomicAdd(&fill[d], 1);
    csr_src[pos] = s;
    csr_w[pos] = dinv[s] * dinv[d];
}

// ---------------------------------------------------------------------------
// Fused gather (fp16 hw) + self-loop + bias + BN(eval) + relu + residual.
// One 64-lane wave per dst node; lane owns 4 contiguous halves (8B loads).
// ---------------------------------------------------------------------------
__global__ __launch_bounds__(256) void gather_fused_kernel(
    const int* __restrict__ offs, const int* __restrict__ degi,
    const int* __restrict__ csr_src, const float* __restrict__ csr_w,
    const f16* __restrict__ hw, const float* __restrict__ snorm,
    const float* __restrict__ bias, const float* __restrict__ gamma,
    const float* __restrict__ beta, float* __restrict__ h)
{
    const int w = (blockIdx.x * 256 + threadIdx.x) >> 6;
    const int lane = threadIdx.x & 63;
    if (w >= N_NODES) return;
    const int start = offs[w];
    const int cnt = degi[w];
    const int col = lane * 4;

    float4 acc = make_float4(0.f, 0.f, 0.f, 0.f);
    int i = 0;
    for (; i + 2 <= cnt; i += 2) {
        const int   s0 = csr_src[start + i];
        const int   s1 = csr_src[start + i + 1];
        const float w0 = csr_w[start + i];
        const float w1 = csr_w[start + i + 1];
        const f16x4 v0 = *(const f16x4*)(hw + (size_t)s0 * HID + col);
        const f16x4 v1 = *(const f16x4*)(hw + (size_t)s1 * HID + col);
        acc.x = fmaf((float)v0[0], w0, acc.x); acc.y = fmaf((float)v0[1], w0, acc.y);
        acc.z = fmaf((float)v0[2], w0, acc.z); acc.w = fmaf((float)v0[3], w0, acc.w);
        acc.x = fmaf((float)v1[0], w1, acc.x); acc.y = fmaf((float)v1[1], w1, acc.y);
        acc.z = fmaf((float)v1[2], w1, acc.z); acc.w = fmaf((float)v1[3], w1, acc.w);
    }
    if (i < cnt) {
        const int   s0 = csr_src[start + i];
        const float w0 = csr_w[start + i];
        const f16x4 v0 = *(const f16x4*)(hw + (size_t)s0 * HID + col);
        acc.x = fmaf((float)v0[0], w0, acc.x); acc.y = fmaf((float)v0[1], w0, acc.y);
        acc.z = fmaf((float)v0[2], w0, acc.z); acc.w = fmaf((float)v0[3], w0, acc.w);
    }

    // self-loop term
    const float sn = snorm[w];
    const f16x4 hwv = *(const f16x4*)(hw + (size_t)w * HID + col);
    acc.x = fmaf((float)hwv[0], sn, acc.x); acc.y = fmaf((float)hwv[1], sn, acc.y);
    acc.z = fmaf((float)hwv[2], sn, acc.z); acc.w = fmaf((float)hwv[3], sn, acc.w);

    // bias + BN + relu + residual
    const float4 b4 = *(const float4*)&bias[col];
    const float4 g4 = *(const float4*)&gamma[col];
    const float4 t4 = *(const float4*)&beta[col];
    float* hp = h + (size_t)w * HID + col;
    float4 hv = *(float4*)hp;
    hv.x += fmaxf((acc.x + b4.x) * g4.x + t4.x, 0.f);
    hv.y += fmaxf((acc.y + b4.y) * g4.y + t4.y, 0.f);
    hv.z += fmaxf((acc.z + b4.z) * g4.z + t4.z, 0.f);
    hv.w += fmaxf((acc.w + b4.w) * g4.w + t4.w, 0.f);
    *(float4*)hp = hv;
}

// ---------------------------------------------------------------------------
extern "C" void kernel_launch(void* const* d_in, const int* in_sizes, int n_in,
                              void* d_out, int out_size, void* d_ws, size_t ws_size,
                              hipStream_t stream)
{
    const float* x        = (const float*)d_in[0];
    const int*   ei       = (const int*)d_in[1];      // [2, E]
    const float* embed_W  = (const float*)d_in[2];
    const float* embed_b  = (const float*)d_in[3];
    const float* conv_W   = (const float*)d_in[4];    // [3,256,256]
    const float* conv_b   = (const float*)d_in[5];
    const float* bn_gamma = (const float*)d_in[6];
    const float* bn_beta  = (const float*)d_in[7];
    const float* cls_W0   = (const float*)d_in[8];
    const float* cls_b0   = (const float*)d_in[9];
    const float* cls_W1   = (const float*)d_in[10];
    const float* cls_b1   = (const float*)d_in[11];
    const float* cls_W2   = (const float*)d_in[12];
    const float* cls_b2   = (const float*)d_in[13];
    const float* cls_W3   = (const float*)d_in[14];
    const float* cls_b3   = (const float*)d_in[15];
    float* out = (float*)d_out;

    const int* e_src = ei;
    const int* e_dst = ei + N_EDGES;

    // ---- workspace layout (all chunks 16B-aligned) ----
    char* p = (char*)d_ws;
    int*   deg_i   = (int*)p;                 p += (size_t)N_NODES * 4;   // memset
    int*   fillc   = (int*)p;                 p += (size_t)N_NODES * 4;   // together
    int*   offs    = (int*)p;                 p += (size_t)N_NODES * 4;
    int*   bsum    = (int*)p;                 p += 512 * 4;
    float* dinv    = (float*)p;               p += (size_t)N_NODES * 4;
    float* snorm   = (float*)p;               p += (size_t)N_NODES * 4;
    int*   csr_src = (int*)p;                 p += (size_t)N_EDGES * 4;
    float* csr_w   = (float*)p;               p += (size_t)N_EDGES * 4;
    float* h       = (float*)p;               p += (size_t)N_NODES * HID * 4;
    f16*   hw16    = (f16*)p;                 p += (size_t)N_NODES * HID * 2;
    float* mlpA    = (float*)p;               p += (size_t)N_NODES * 128 * 4;
    float* mlpB    = (float*)p;               p += (size_t)N_NODES * 64 * 4;
    f16*   Wt_e    = (f16*)p;                 p += (size_t)256 * 512 * 2;
    f16*   Wt_c    = (f16*)p;                 p += (size_t)3 * 256 * 256 * 2;
    f16*   Wt_0    = (f16*)p;                 p += (size_t)128 * 256 * 2;

    const int NB_N = (N_NODES + 255) / 256;   // 391
    const int NB_E = (N_EDGES + 255) / 256;   // 6250

    // ---- degree / norms / CSR build ----
    hipMemsetAsync(deg_i, 0, (size_t)2 * N_NODES * sizeof(int), stream);
    deg_kernel<<<NB_E, 256, 0, stream>>>(e_dst, deg_i);
    norm_kernel<<<NB_N, 256, 0, stream>>>(deg_i, dinv, snorm);
    scan1_kernel<<<NB_N, 256, 0, stream>>>(deg_i, offs, bsum, N_NODES);
    scan2_kernel<<<1, 512, 0, stream>>>(bsum, NB_N);
    scan3_kernel<<<NB_N, 256, 0, stream>>>(offs, bsum, N_NODES);
    fill_kernel<<<NB_E, 256, 0, stream>>>(e_src, e_dst, offs, fillc, dinv,
                                          csr_src, csr_w);

    // ---- weight transpose + fp16 convert ----
    wt_kernel<<<(256 * 512 + 255) / 256, 256, 0, stream>>>(embed_W, Wt_e, IN_DIM, HID, 512);
    for (int l = 0; l < N_LAYERS; ++l)
        wt_kernel<<<(256 * 256 + 255) / 256, 256, 0, stream>>>(
            conv_W + (size_t)l * HID * HID, Wt_c + (size_t)l * HID * HID, HID, HID, HID);
    wt_kernel<<<(128 * 256 + 255) / 256, 256, 0, stream>>>(cls_W0, Wt_0, 256, 128, 256);

    const int MB = (N_NODES + 127) / 128;   // 782
    const int MT = (N_NODES + 63) / 64;     // 1563

    // ---- embed: h = x @ embed_W + embed_b (MFMA fp16) ----
    mfma_gemm_kernel<0><<<dim3(MB, 2), 256, 0, stream>>>(
        x, Wt_e, embed_b, h, N_NODES, HID, IN_DIM, 512);

    // ---- GCN layers ----
    for (int l = 0; l < N_LAYERS; ++l) {
        mfma_gemm_kernel<4><<<dim3(MB, 2), 256, 0, stream>>>(
            h, Wt_c + (size_t)l * HID * HID, nullptr, hw16, N_NODES, HID, HID, HID);
        gather_fused_kernel<<<(N_NODES * 64 + 255) / 256, 256, 0, stream>>>(
            offs, deg_i, csr_src, csr_w, hw16, snorm,
            conv_b + l * HID, bn_gamma + l * HID, bn_beta + l * HID, h);
    }

    // ---- classifier MLP ----
    mfma_gemm_kernel<1><<<dim3(MB, 1), 256, 0, stream>>>(
        h, Wt_0, cls_b0, mlpA, N_NODES, 128, 256, 256);
    gemm_kernel<1><<<dim3(MT, 1), 256, 0, stream>>>(
        mlpA, cls_W1, cls_b1, mlpB, N_NODES, 64, 128);
    gemm_kernel<1><<<dim3(MT, 1), 256, 0, stream>>>(
        mlpB, cls_W2, cls_b2, mlpA, N_NODES, 32, 64);
    gemm_kernel<0><<<dim3(MT, 1), 256, 0, stream>>>(
        mlpA, cls_W3, cls_b3, out, N_NODES, N_CLASSES, 32);
}

// Round 5
// 1217.612 us; speedup vs baseline: 14.2841x; 1.0724x over previous
//
#include <hip/hip_runtime.h>

#define N_NODES  100000
#define N_EDGES  1600000
#define IN_DIM   500
#define HID      256
#define N_LAYERS 3
#define N_CLASSES 40

typedef _Float16 f16;
typedef __attribute__((ext_vector_type(8))) _Float16 f16x8;
typedef __attribute__((ext_vector_type(4))) _Float16 f16x4;
typedef __attribute__((ext_vector_type(4))) float    f32x4;

// ---------------------------------------------------------------------------
// MFMA fp16 GEMM, double-buffered, BM=128, BN templated (128/256), BK=32.
// Threads = 2*BN (4 or 8 waves), wave tile 64x64 (acc 4x4 of 16x16x32).
// A: fp32 (converted in staging) if !AF16, else fp16 row-major [M][K].
// Bt: fp16 [BN][KP] (pre-transposed, K zero-padded to KP).
// MODE 0: fp32 C + bias, plus fp16 copy C16    (embed -> h, h16)
// MODE 1: fp32 C + bias + relu                 (cls0 -> mlpA)
// MODE 4: fp16 C only                          (conv -> hw16)
// grid = (ceil(M/128), 1): BN == N exactly at every call site.
// LDS pad: row stride 40 halves (80B) -> fragment reads are 2-way (free).
// ---------------------------------------------------------------------------
template <int MODE, int BN, bool AF16>
__global__ __launch_bounds__(BN * 2) void mgemm_kernel(
    const void* __restrict__ Ain, const f16* __restrict__ Bt,
    const float* __restrict__ bias, void* __restrict__ Cout,
    f16* __restrict__ C16, int M, int K, int KP)
{
    constexpr int T   = BN * 2;      // threads
    constexpr int ACH = 256 / BN;    // A row-chunks per thread
    constexpr int RPC = T / 4;       // rows covered per chunk pass
    constexpr int WC  = BN / 64;     // wave columns

    __shared__ f16 Ah[2][128][40];
    __shared__ f16 Bs[2][BN][40];

    const int tid  = threadIdx.x;
    const int lane = tid & 63;
    const int wv   = tid >> 6;
    const int wr   = wv / WC;
    const int wc   = wv % WC;
    const int m0   = blockIdx.x * 128;
    const int srow = tid >> 2;
    const int sc8  = (tid & 3) * 8;

    const float* Af  = (const float*)Ain;
    const f16*   A16 = (const f16*)Ain;

    f32x4 acc[4][4];
    #pragma unroll
    for (int i = 0; i < 4; ++i)
        #pragma unroll
        for (int j = 0; j < 4; ++j)
            acc[i][j] = (f32x4){0.f, 0.f, 0.f, 0.f};

    float4 laL[ACH], laH[ACH];
    f16x8  la16[ACH];
    f16x8  lb[2];

    const int nt = KP / 32;

    auto load_regs = [&](int t) {
        const int kb = t * 32 + sc8;
        #pragma unroll
        for (int i = 0; i < ACH; ++i) {
            const int m = m0 + srow + i * RPC;
            if (AF16) {
                f16x8 v;
                #pragma unroll
                for (int q = 0; q < 8; ++q) v[q] = (f16)0.f;
                if (m < M && kb + 8 <= K)
                    v = *(const f16x8*)&A16[(size_t)m * K + kb];
                la16[i] = v;
            } else {
                float4 lo = make_float4(0.f, 0.f, 0.f, 0.f);
                float4 hi = make_float4(0.f, 0.f, 0.f, 0.f);
                if (m < M) {
                    if (kb + 4 <= K) lo = *(const float4*)&Af[(size_t)m * K + kb];
                    if (kb + 8 <= K) hi = *(const float4*)&Af[(size_t)m * K + kb + 4];
                }
                laL[i] = lo; laH[i] = hi;
            }
        }
        #pragma unroll
        for (int i = 0; i < 2; ++i) {
            const int r = srow + i * RPC;
            lb[i] = *(const f16x8*)&Bt[(size_t)r * KP + kb];
        }
    };

    auto write_lds = [&](int buf) {
        #pragma unroll
        for (int i = 0; i < ACH; ++i) {
            const int r = srow + i * RPC;
            f16x8 hv;
            if (AF16) {
                hv = la16[i];
            } else {
                hv[0] = (f16)laL[i].x; hv[1] = (f16)laL[i].y;
                hv[2] = (f16)laL[i].z; hv[3] = (f16)laL[i].w;
                hv[4] = (f16)laH[i].x; hv[5] = (f16)laH[i].y;
                hv[6] = (f16)laH[i].z; hv[7] = (f16)laH[i].w;
            }
            *(f16x8*)&Ah[buf][r][sc8] = hv;
        }
        #pragma unroll
        for (int i = 0; i < 2; ++i)
            *(f16x8*)&Bs[buf][srow + i * RPC][sc8] = lb[i];
    };

    load_regs(0);
    write_lds(0);
    __syncthreads();

    for (int t = 0; t < nt; ++t) {
        if (t + 1 < nt) load_regs(t + 1);   // issue next-tile loads early (T14)
        const int buf = t & 1;
        const int fr = lane & 15;
        const int fg = (lane >> 4) * 8;
        f16x8 af[4], bf[4];
        #pragma unroll
        for (int i = 0; i < 4; ++i)
            af[i] = *(const f16x8*)&Ah[buf][wr * 64 + i * 16 + fr][fg];
        #pragma unroll
        for (int j = 0; j < 4; ++j)
            bf[j] = *(const f16x8*)&Bs[buf][wc * 64 + j * 16 + fr][fg];
        #pragma unroll
        for (int i = 0; i < 4; ++i)
            #pragma unroll
            for (int j = 0; j < 4; ++j)
                acc[i][j] = __builtin_amdgcn_mfma_f32_16x16x32_f16(
                    af[i], bf[j], acc[i][j], 0, 0, 0);
        __syncthreads();
        if (t + 1 < nt) {
            write_lds((t + 1) & 1);
            __syncthreads();
        }
    }

    // ---- epilogue: C/D layout col=lane&15, row=(lane>>4)*4+reg ----
    const int fr = lane & 15;
    const int rg = (lane >> 4) * 4;
    #pragma unroll
    for (int i = 0; i < 4; ++i) {
        #pragma unroll
        for (int j = 0; j < 4; ++j) {
            const int col = wc * 64 + j * 16 + fr;
            const float b = (MODE == 0 || MODE == 1) ? bias[col] : 0.f;
            #pragma unroll
            for (int r = 0; r < 4; ++r) {
                const int m = m0 + wr * 64 + i * 16 + rg + r;
                if (m >= M) continue;
                float v = acc[i][j][r] + b;
                if (MODE == 1) v = fmaxf(v, 0.f);
                if (MODE == 4) {
                    ((f16*)Cout)[(size_t)m * BN + col] = (f16)v;
                } else {
                    ((float*)Cout)[(size_t)m * BN + col] = v;
                    if (MODE == 0) C16[(size_t)m * BN + col] = (f16)v;
                }
            }
        }
    }
}

// ---------------------------------------------------------------------------
// Weight transpose + fp16 convert: W[K][N] fp32 -> Wt[N][KP] fp16 (zero pad)
// ---------------------------------------------------------------------------
__global__ __launch_bounds__(256) void wt_kernel(
    const float* __restrict__ W, f16* __restrict__ Wt, int K, int N, int KP)
{
    const int i = blockIdx.x * 256 + threadIdx.x;
    if (i >= N * KP) return;
    const int n = i / KP;
    const int k = i - n * KP;
    Wt[i] = (k < K) ? (f16)W[(size_t)k * N + n] : (f16)0.f;
}

// ---------------------------------------------------------------------------
// Tiled fp32 GEMM for the small MLP tail (N<=64).
// MODE 0: C = A@B + bias   MODE 1: C = relu(A@B + bias)
// ---------------------------------------------------------------------------
template <int MODE>
__global__ __launch_bounds__(256) void gemm_kernel(
    const float* __restrict__ A, const float* __restrict__ B,
    const float* __restrict__ bias, float* __restrict__ C,
    int M, int N, int K)
{
    __shared__ float As[16][68];
    __shared__ float Bsh[16][68];

    const int tid = threadIdx.x;
    const int tx = tid & 15;
    const int ty = tid >> 4;
    const int bm = blockIdx.x * 64;
    const int bn = blockIdx.y * 64;

    const int ar = tid >> 2;
    const int ac = (tid & 3) * 4;
    const int br = tid >> 4;
    const int bc = (tid & 15) * 4;

    float c[4][4] = {};

    for (int k0 = 0; k0 < K; k0 += 16) {
        {
            const int m = bm + ar;
            const int k = k0 + ac;
            float4 av = make_float4(0.f, 0.f, 0.f, 0.f);
            if (m < M && k < K) av = *(const float4*)&A[(size_t)m * K + k];
            As[ac + 0][ar] = av.x;
            As[ac + 1][ar] = av.y;
            As[ac + 2][ar] = av.z;
            As[ac + 3][ar] = av.w;
        }
        {
            const int k = k0 + br;
            const int n = bn + bc;
            float4 bv = make_float4(0.f, 0.f, 0.f, 0.f);
            if (k < K && n < N) bv = *(const float4*)&B[(size_t)k * N + n];
            Bsh[br][bc + 0] = bv.x;
            Bsh[br][bc + 1] = bv.y;
            Bsh[br][bc + 2] = bv.z;
            Bsh[br][bc + 3] = bv.w;
        }
        __syncthreads();

        #pragma unroll
        for (int kk = 0; kk < 16; ++kk) {
            const float4 av = *(const float4*)&As[kk][ty * 4];
            const float4 bv = *(const float4*)&Bsh[kk][tx * 4];
            const float a[4] = {av.x, av.y, av.z, av.w};
            const float b[4] = {bv.x, bv.y, bv.z, bv.w};
            #pragma unroll
            for (int i = 0; i < 4; ++i)
                #pragma unroll
                for (int j = 0; j < 4; ++j)
                    c[i][j] = fmaf(a[i], b[j], c[i][j]);
        }
        __syncthreads();
    }

    const int n = bn + tx * 4;
    if (n >= N) return;
    const float4 bias4 = *(const float4*)&bias[n];

    #pragma unroll
    for (int i = 0; i < 4; ++i) {
        const int m = bm + ty * 4 + i;
        if (m >= M) continue;
        float4 v = make_float4(c[i][0] + bias4.x, c[i][1] + bias4.y,
                               c[i][2] + bias4.z, c[i][3] + bias4.w);
        if (MODE == 1) {
            v.x = fmaxf(v.x, 0.f); v.y = fmaxf(v.y, 0.f);
            v.z = fmaxf(v.z, 0.f); v.w = fmaxf(v.w, 0.f);
        }
        *(float4*)&C[(size_t)m * N + n] = v;
    }
}

// ---------------------------------------------------------------------------
// degree histogram over dst (int, deg pre-zeroed)
// ---------------------------------------------------------------------------
__global__ __launch_bounds__(256) void deg_kernel(
    const int* __restrict__ dst, int* __restrict__ deg)
{
    const int i = blockIdx.x * 256 + threadIdx.x;
    if (i < N_EDGES) atomicAdd(&deg[dst[i]], 1);
}

__global__ __launch_bounds__(256) void norm_kernel(
    const int* __restrict__ deg, float* __restrict__ dinv,
    float* __restrict__ selfnorm)
{
    const int i = blockIdx.x * 256 + threadIdx.x;
    if (i < N_NODES) {
        const float d = (float)deg[i] + 1.0f;
        dinv[i] = 1.0f / sqrtf(d);
        selfnorm[i] = 1.0f / d;
    }
}

// ---------------------------------------------------------------------------
// 3-step exclusive scan of deg -> offs
// ---------------------------------------------------------------------------
__global__ __launch_bounds__(256) void scan1_kernel(
    const int* __restrict__ deg, int* __restrict__ offs,
    int* __restrict__ bsum, int n)
{
    __shared__ int tmp[256];
    const int i = blockIdx.x * 256 + threadIdx.x;
    const int v = (i < n) ? deg[i] : 0;
    tmp[threadIdx.x] = v;
    __syncthreads();
    #pragma unroll
    for (int off = 1; off < 256; off <<= 1) {
        const int t = (threadIdx.x >= off) ? tmp[threadIdx.x - off] : 0;
        __syncthreads();
        tmp[threadIdx.x] += t;
        __syncthreads();
    }
    const int inc = tmp[threadIdx.x];
    if (i < n) offs[i] = inc - v;
    if (threadIdx.x == 255) bsum[blockIdx.x] = inc;
}

__global__ __launch_bounds__(512) void scan2_kernel(int* __restrict__ bsum, int nb)
{
    __shared__ int tmp[512];
    const int i = threadIdx.x;
    const int v = (i < nb) ? bsum[i] : 0;
    tmp[i] = v;
    __syncthreads();
    #pragma unroll
    for (int off = 1; off < 512; off <<= 1) {
        const int t = (i >= off) ? tmp[i - off] : 0;
        __syncthreads();
        tmp[i] += t;
        __syncthreads();
    }
    if (i < nb) bsum[i] = tmp[i] - v;
}

__global__ __launch_bounds__(256) void scan3_kernel(
    int* __restrict__ offs, const int* __restrict__ bsum, int n)
{
    const int i = blockIdx.x * 256 + threadIdx.x;
    if (i < n) offs[i] += bsum[blockIdx.x];
}

// ---------------------------------------------------------------------------
// CSR bucket fill
// ---------------------------------------------------------------------------
__global__ __launch_bounds__(256) void fill_kernel(
    const int* __restrict__ src, const int* __restrict__ dst,
    const int* __restrict__ offs, int* __restrict__ fill,
    const float* __restrict__ dinv,
    int* __restrict__ csr_src, float* __restrict__ csr_w)
{
    const int e = blockIdx.x * 256 + threadIdx.x;
    if (e >= N_EDGES) return;
    const int s = src[e];
    const int d = dst[e];
    const int pos = offs[d] + atomicAdd(&fill[d], 1);
    csr_src[pos] = s;
    csr_w[pos] = dinv[s] * dinv[d];
}

// ---------------------------------------------------------------------------
// Fused gather (fp16 hw) + self-loop + bias + BN(eval) + relu + residual.
// Writes both fp32 h (residual stream) and fp16 h16 (next GEMM's A).
// One 64-lane wave per dst node; lane owns 4 contiguous channels.
// ---------------------------------------------------------------------------
__global__ __launch_bounds__(256) void gather_fused_kernel(
    const int* __restrict__ offs, const int* __restrict__ degi,
    const int* __restrict__ csr_src, const float* __restrict__ csr_w,
    const f16* __restrict__ hw, const float* __restrict__ snorm,
    const float* __restrict__ bias, const float* __restrict__ gamma,
    const float* __restrict__ beta, float* __restrict__ h,
    f16* __restrict__ h16)
{
    const int w = (blockIdx.x * 256 + threadIdx.x) >> 6;
    const int lane = threadIdx.x & 63;
    if (w >= N_NODES) return;
    const int start = offs[w];
    const int cnt = degi[w];
    const int col = lane * 4;

    float4 acc = make_float4(0.f, 0.f, 0.f, 0.f);
    int i = 0;
    for (; i + 2 <= cnt; i += 2) {
        const int   s0 = csr_src[start + i];
        const int   s1 = csr_src[start + i + 1];
        const float w0 = csr_w[start + i];
        const float w1 = csr_w[start + i + 1];
        const f16x4 v0 = *(const f16x4*)(hw + (size_t)s0 * HID + col);
        const f16x4 v1 = *(const f16x4*)(hw + (size_t)s1 * HID + col);
        acc.x = fmaf((float)v0[0], w0, acc.x); acc.y = fmaf((float)v0[1], w0, acc.y);
        acc.z = fmaf((float)v0[2], w0, acc.z); acc.w = fmaf((float)v0[3], w0, acc.w);
        acc.x = fmaf((float)v1[0], w1, acc.x); acc.y = fmaf((float)v1[1], w1, acc.y);
        acc.z = fmaf((float)v1[2], w1, acc.z); acc.w = fmaf((float)v1[3], w1, acc.w);
    }
    if (i < cnt) {
        const int   s0 = csr_src[start + i];
        const float w0 = csr_w[start + i];
        const f16x4 v0 = *(const f16x4*)(hw + (size_t)s0 * HID + col);
        acc.x = fmaf((float)v0[0], w0, acc.x); acc.y = fmaf((float)v0[1], w0, acc.y);
        acc.z = fmaf((float)v0[2], w0, acc.z); acc.w = fmaf((float)v0[3], w0, acc.w);
    }

    // self-loop term
    const float sn = snorm[w];
    const f16x4 hwv = *(const f16x4*)(hw + (size_t)w * HID + col);
    acc.x = fmaf((float)hwv[0], sn, acc.x); acc.y = fmaf((float)hwv[1], sn, acc.y);
    acc.z = fmaf((float)hwv[2], sn, acc.z); acc.w = fmaf((float)hwv[3], sn, acc.w);

    // bias + BN + relu + residual
    const float4 b4 = *(const float4*)&bias[col];
    const float4 g4 = *(const float4*)&gamma[col];
    const float4 t4 = *(const float4*)&beta[col];
    float* hp = h + (size_t)w * HID + col;
    float4 hv = *(float4*)hp;
    hv.x += fmaxf((acc.x + b4.x) * g4.x + t4.x, 0.f);
    hv.y += fmaxf((acc.y + b4.y) * g4.y + t4.y, 0.f);
    hv.z += fmaxf((acc.z + b4.z) * g4.z + t4.z, 0.f);
    hv.w += fmaxf((acc.w + b4.w) * g4.w + t4.w, 0.f);
    *(float4*)hp = hv;

    f16x4 h4;
    h4[0] = (f16)hv.x; h4[1] = (f16)hv.y; h4[2] = (f16)hv.z; h4[3] = (f16)hv.w;
    *(f16x4*)(h16 + (size_t)w * HID + col) = h4;
}

// ---------------------------------------------------------------------------
extern "C" void kernel_launch(void* const* d_in, const int* in_sizes, int n_in,
                              void* d_out, int out_size, void* d_ws, size_t ws_size,
                              hipStream_t stream)
{
    const float* x        = (const float*)d_in[0];
    const int*   ei       = (const int*)d_in[1];      // [2, E]
    const float* embed_W  = (const float*)d_in[2];
    const float* embed_b  = (const float*)d_in[3];
    const float* conv_W   = (const float*)d_in[4];    // [3,256,256]
    const float* conv_b   = (const float*)d_in[5];
    const float* bn_gamma = (const float*)d_in[6];
    const float* bn_beta  = (const float*)d_in[7];
    const float* cls_W0   = (const float*)d_in[8];
    const float* cls_b0   = (const float*)d_in[9];
    const float* cls_W1   = (const float*)d_in[10];
    const float* cls_b1   = (const float*)d_in[11];
    const float* cls_W2   = (const float*)d_in[12];
    const float* cls_b2   = (const float*)d_in[13];
    const float* cls_W3   = (const float*)d_in[14];
    const float* cls_b3   = (const float*)d_in[15];
    float* out = (float*)d_out;

    const int* e_src = ei;
    const int* e_dst = ei + N_EDGES;

    // ---- workspace layout (16B-aligned chunks) ----
    char* p = (char*)d_ws;
    int*   deg_i   = (int*)p;                 p += (size_t)N_NODES * 4;   // memset
    int*   fillc   = (int*)p;                 p += (size_t)N_NODES * 4;   // together
    int*   offs    = (int*)p;                 p += (size_t)N_NODES * 4;
    int*   bsum    = (int*)p;                 p += 512 * 4;
    float* dinv    = (float*)p;               p += (size_t)N_NODES * 4;
    float* snorm   = (float*)p;               p += (size_t)N_NODES * 4;
    int*   csr_src = (int*)p;                 p += (size_t)N_EDGES * 4;
    float* csr_w   = (float*)p;               p += (size_t)N_EDGES * 4;
    float* h       = (float*)p;               p += (size_t)N_NODES * HID * 4;
    f16*   h16     = (f16*)p;                 p += (size_t)N_NODES * HID * 2;
    f16*   hw16    = (f16*)p;                 p += (size_t)N_NODES * HID * 2;
    float* mlpA    = (float*)p;               p += (size_t)N_NODES * 128 * 4;
    float* mlpB    = (float*)p;               p += (size_t)N_NODES * 64 * 4;
    f16*   Wt_e    = (f16*)p;                 p += (size_t)256 * 512 * 2;
    f16*   Wt_c    = (f16*)p;                 p += (size_t)3 * 256 * 256 * 2;
    f16*   Wt_0    = (f16*)p;                 p += (size_t)128 * 256 * 2;

    const int NB_N = (N_NODES + 255) / 256;   // 391
    const int NB_E = (N_EDGES + 255) / 256;   // 6250

    // ---- degree / norms / CSR build ----
    hipMemsetAsync(deg_i, 0, (size_t)2 * N_NODES * sizeof(int), stream);
    deg_kernel<<<NB_E, 256, 0, stream>>>(e_dst, deg_i);
    norm_kernel<<<NB_N, 256, 0, stream>>>(deg_i, dinv, snorm);
    scan1_kernel<<<NB_N, 256, 0, stream>>>(deg_i, offs, bsum, N_NODES);
    scan2_kernel<<<1, 512, 0, stream>>>(bsum, NB_N);
    scan3_kernel<<<NB_N, 256, 0, stream>>>(offs, bsum, N_NODES);
    fill_kernel<<<NB_E, 256, 0, stream>>>(e_src, e_dst, offs, fillc, dinv,
                                          csr_src, csr_w);

    // ---- weight transpose + fp16 convert ----
    wt_kernel<<<(256 * 512 + 255) / 256, 256, 0, stream>>>(embed_W, Wt_e, IN_DIM, HID, 512);
    for (int l = 0; l < N_LAYERS; ++l)
        wt_kernel<<<(256 * 256 + 255) / 256, 256, 0, stream>>>(
            conv_W + (size_t)l * HID * HID, Wt_c + (size_t)l * HID * HID, HID, HID, HID);
    wt_kernel<<<(128 * 256 + 255) / 256, 256, 0, stream>>>(cls_W0, Wt_0, 256, 128, 256);

    const int MB = (N_NODES + 127) / 128;   // 782
    const int MT = (N_NODES + 63) / 64;     // 1563

    // ---- embed: h = x @ embed_W + embed_b (fp32 A, writes h + h16) ----
    mgemm_kernel<0, 256, false><<<MB, 512, 0, stream>>>(
        x, Wt_e, embed_b, h, h16, N_NODES, IN_DIM, 512);

    // ---- GCN layers ----
    for (int l = 0; l < N_LAYERS; ++l) {
        mgemm_kernel<4, 256, true><<<MB, 512, 0, stream>>>(
            h16, Wt_c + (size_t)l * HID * HID, nullptr, hw16, nullptr,
            N_NODES, HID, HID);
        gather_fused_kernel<<<(N_NODES * 64 + 255) / 256, 256, 0, stream>>>(
            offs, deg_i, csr_src, csr_w, hw16, snorm,
            conv_b + l * HID, bn_gamma + l * HID, bn_beta + l * HID, h, h16);
    }

    // ---- classifier MLP ----
    mgemm_kernel<1, 128, true><<<MB, 256, 0, stream>>>(
        h16, Wt_0, cls_b0, mlpA, nullptr, N_NODES, HID, HID);
    gemm_kernel<1><<<dim3(MT, 1), 256, 0, stream>>>(
        mlpA, cls_W1, cls_b1, mlpB, N_NODES, 64, 128);
    gemm_kernel<1><<<dim3(MT, 1), 256, 0, stream>>>(
        mlpB, cls_W2, cls_b2, mlpA, N_NODES, 32, 64);
    gemm_kernel<0><<<dim3(MT, 1), 256, 0, stream>>>(
        mlpA, cls_W3, cls_b3, out, N_NODES, N_CLASSES, 32);
}